// Round 1
// baseline (519.616 us; speedup 1.0000x reference)
//
#include <hip/hip_runtime.h>

// out[b, f, i, j] = relu(w0[f]*t[b,i] + w1[f]*t[b,j] + w2[f])
// t: (BSZ, SZ) f32, w: (1, NF, 3, 1) f32, out: (BSZ, NF, SZ*SZ) f32
// Pure write-BW-bound: 512 MiB out, ~32 KB in. Kernel floor ~86 us @ 6.2 TB/s.
//
// R3 theory: timed dur (516 us) includes harness poison fills (~347 us for
// the 2 GiB ws fill alone, per rocprof); pairwise_kernel itself is < 341 us
// (absent from top-5). Remaining ambiguity: kernel at ~86 us (floor) vs
// ~170 us (3.2 TB/s, lgkm-stalled store stream). This version removes the
// per-iteration LDS dependence: all 32 broadcast ai[] reads are hoisted
// into registers before the store loop, making the 32 dwordx4 stores fully
// independent (same MLP shape as the 6.2 TB/s harness fill kernel).
// If dur drops to ~433 -> H(b) confirmed. If unchanged -> kernel was at
// floor, declare roofline (residual is harness poison overhead).

#define BSZ 16
#define SZ  512
#define NF  32

constexpr int ROWS_PER_BLOCK = 64;
constexpr int CHUNKS = SZ / ROWS_PER_BLOCK;   // 8
constexpr int BLOCK  = 256;
constexpr int ITERS  = ROWS_PER_BLOCK / 2;    // 32 rows per thread (stride 2)

typedef float vfloat4 __attribute__((ext_vector_type(4)));

__global__ __launch_bounds__(BLOCK) void pairwise_kernel(
    const float* __restrict__ t, const float* __restrict__ w,
    float* __restrict__ out)
{
    __shared__ float tj[SZ];                // w1[f] * t[b, :]
    __shared__ float ai[ROWS_PER_BLOCK];    // w0[f] * t[b, row0+r] + w2[f]

    const int blk   = blockIdx.x;           // b*(NF*CHUNKS) + f*CHUNKS + chunk
    const int chunk = blk & (CHUNKS - 1);
    const int f     = (blk >> 3) & (NF - 1);
    const int b     = blk >> 8;             // 3 + 5 bits

    const float w0 = w[f * 3 + 0];
    const float w1 = w[f * 3 + 1];
    const float w2 = w[f * 3 + 2];

    const float* tb = t + b * SZ;
    const int row0 = chunk * ROWS_PER_BLOCK;

    // Stage scaled row vector and per-row affine terms into LDS.
    for (int idx = threadIdx.x; idx < SZ; idx += BLOCK)
        tj[idx] = w1 * tb[idx];
    if (threadIdx.x < ROWS_PER_BLOCK)
        ai[threadIdx.x] = w0 * tb[row0 + threadIdx.x] + w2;
    __syncthreads();

    const int col4 = threadIdx.x & 127;     // 0..127 -> column group of 4
    const int rsub = threadIdx.x >> 7;      // 0..1
    const vfloat4 c = ((const vfloat4*)tj)[col4];   // loop-invariant per thread

    // Hoist ALL per-row affine terms into registers first: 32 broadcast
    // LDS reads with no stores interleaved. The store loop below then has
    // zero lgkmcnt dependence -> pure independent store stream.
    float a[ITERS];
    #pragma unroll
    for (int k = 0; k < ITERS; ++k)
        a[k] = ai[rsub + 2 * k];

    vfloat4* op = (vfloat4*)(out + ((size_t)(b * NF + f) * SZ + row0) * SZ)
                  + (size_t)rsub * (SZ / 4) + col4;

    #pragma unroll
    for (int k = 0; k < ITERS; ++k) {
        vfloat4 o;
        o.x = fmaxf(a[k] + c.x, 0.0f);
        o.y = fmaxf(a[k] + c.y, 0.0f);
        o.z = fmaxf(a[k] + c.z, 0.0f);
        o.w = fmaxf(a[k] + c.w, 0.0f);
        op[(size_t)k * (2 * SZ / 4)] = o;   // row stride 2 (rsub interleave)
    }
}

extern "C" void kernel_launch(void* const* d_in, const int* in_sizes, int n_in,
                              void* d_out, int out_size, void* d_ws, size_t ws_size,
                              hipStream_t stream) {
    const float* t = (const float*)d_in[0];
    const float* w = (const float*)d_in[1];
    float* out = (float*)d_out;

    const int grid = BSZ * NF * CHUNKS;     // 4096 blocks
    pairwise_kernel<<<dim3(grid), dim3(BLOCK), 0, stream>>>(t, w, out);
}